// Round 1
// baseline (156.250 us; speedup 1.0000x reference)
//
#include <hip/hip_runtime.h>

// MVB (minimum-variance beamformer), fp32.
// B=2, C=128, NS=1024, NZ=256, NX=128, L_SUB=16, M=113.
//
// Design:
//  - 1 thread per output pixel; block = 128 threads = one (b,z) row of x.
//  - rf rows staged to LDS in double-buffered chunks of 8 rows (global float4
//    loads prefetched one chunk ahead, ds_write_b128), gathers hit LDS.
//  - R via lag-correlation identity: R[l][l+d] = F[d] - head/tail corrections,
//    F[d] accumulated with a 16-deep rolling register window (2048 FMAs).
//  - 1/M scaling dropped (w = u/sum(u) is scale invariant); 1/113 folded into
//    the final divide. Packed-triangular R (136 regs), fully unrolled Cholesky
//    + forward/back solves per thread.

namespace {

constexpr int kB  = 2;
constexpr int kC  = 128;
constexpr int kNS = 1024;
constexpr int kNZ = 256;
constexpr int kNX = 128;
constexpr int kZX = kNZ * kNX;      // 32768
constexpr int kChunk = 8;           // rf rows per stage
constexpr int kTPB = 128;

// packed upper-triangular index, l <= k, 16x16 -> 136 entries
__device__ __host__ constexpr int tri(int l, int k) {
  return l * 16 - (l * (l - 1)) / 2 + (k - l);
}

template <int PH, bool HEAD>
__device__ __forceinline__ void chunk_compute(
    const float (&rows)[kChunk][kNS], int cbase,
    const float* __restrict__ drx_px, float kk, float base,
    float (&F)[16], float (&win)[16], float (&head)[16], float& Sall) {
  float drx[kChunk];
#pragma unroll
  for (int r = 0; r < kChunk; ++r)
    drx[r] = drx_px[(size_t)(cbase + r) * kZX];   // coalesced across lanes

#pragma unroll
  for (int r = 0; r < kChunk; ++r) {
    const int t = PH + r;                          // == c & 15 (static)
    float pos = fmaf(kk, drx[r], base);
    pos = fminf(fmaxf(pos, 0.0f), 1023.0f);
    int i0 = (int)pos;                             // pos >= 0: trunc == floor
    float frac = pos - (float)i0;
    int i1 = min(i0 + 1, kNS - 1);
    float v0 = rows[r][i0];                        // ds_read, random bank
    float v1 = rows[r][i1];
    float v = fmaf(frac, v1 - v0, v0);
    Sall += v;
    F[0] = fmaf(v, v, F[0]);
    if constexpr (HEAD) {
#pragma unroll
      for (int d = 1; d <= t; ++d) F[d] = fmaf(v, win[t - d], F[d]);
      head[t] = v;
    } else {
#pragma unroll
      for (int d = 1; d < 16; ++d) F[d] = fmaf(v, win[(t - d) & 15], F[d]);
    }
    win[t] = v;
  }
}

__global__ __launch_bounds__(kTPB, 1) void mvb_kernel(
    const float* __restrict__ rf, const float* __restrict__ t0,
    const float* __restrict__ d_tx, const float* __restrict__ d_rx,
    const float* __restrict__ fs_p, const float* __restrict__ c0_p,
    float* __restrict__ out) {
  __shared__ float tile[2][kChunk][kNS];   // 64 KB -> 2 blocks/CU

  const int tid = threadIdx.x;
  const int z = blockIdx.x & (kNZ - 1);
  const int b = blockIdx.x >> 8;           // kNZ == 256
  const int x = tid;

  const float fs = fs_p[0];
  const float c0 = c0_p[0];
  const float kk = fs / c0;
  const float base =
      fs * (d_tx[(size_t)b * kZX + z * kNX + x] / c0 + t0[b]);

  const float* rfb = rf + (size_t)b * kC * kNS;
  const float* drx_px = d_rx + (size_t)z * kNX + x;   // + c*kZX per channel

  float F[16], win[16], head[16];
  float Sall = 0.0f;
#pragma unroll
  for (int i = 0; i < 16; ++i) F[i] = 0.0f;

  float4 pre[kChunk * 2];   // prefetched rf chunk (2 float4 per row per thread)
  auto prefetch = [&](int q) {
    const float* src = rfb + (size_t)q * kChunk * kNS;
#pragma unroll
    for (int r = 0; r < kChunk; ++r) {
      pre[r * 2 + 0] =
          *reinterpret_cast<const float4*>(src + r * kNS + tid * 4);
      pre[r * 2 + 1] =
          *reinterpret_cast<const float4*>(src + r * kNS + 512 + tid * 4);
    }
  };
  auto stage = [&](int buf) {
#pragma unroll
    for (int r = 0; r < kChunk; ++r) {
      *reinterpret_cast<float4*>(&tile[buf][r][tid * 4]) = pre[r * 2 + 0];
      *reinterpret_cast<float4*>(&tile[buf][r][512 + tid * 4]) = pre[r * 2 + 1];
    }
  };

  // ---- pipelined main loop over 16 chunks of 8 channels ----
  prefetch(0);
  stage(0);
  prefetch(1);
  __syncthreads();
  chunk_compute<0, true>(tile[0], 0, drx_px, kk, base, F, win, head, Sall);

  __syncthreads();
  stage(1);
  prefetch(2);
  __syncthreads();
  chunk_compute<8, true>(tile[1], 8, drx_px, kk, base, F, win, head, Sall);

  for (int g = 1; g < 8; ++g) {
    const int q0 = 2 * g;
    __syncthreads();                       // readers of tile[0] (chunk q0-2) done
    stage(0);
    prefetch(q0 + 1);
    __syncthreads();                       // tile[0] visible
    chunk_compute<0, false>(tile[0], q0 * kChunk, drx_px, kk, base, F, win,
                            head, Sall);

    __syncthreads();
    stage(1);
    if (q0 + 2 < 16) prefetch(q0 + 2);
    __syncthreads();
    chunk_compute<8, false>(tile[1], (q0 + 1) * kChunk, drx_px, kk, base, F,
                            win, head, Sall);
  }
  // now: head[i] = xf[i], win[i] = xf[112+i], F[d] = sum_j xf[j]*xf[j-d]

  // ---- assemble R (unscaled by 1/M; packed upper triangle) ----
  float Ru[136];
#pragma unroll
  for (int d = 0; d < 16; ++d) {
    float t0s = 0.0f;                      // tail beyond window of l=0
#pragma unroll
    for (int i = d + 1; i < 16; ++i) t0s = fmaf(win[i - d], win[i], t0s);
    Ru[tri(0, d)] = F[d] - t0s;
#pragma unroll
    for (int l = 1; l < 16 - d; ++l)
      Ru[tri(l, l + d)] = Ru[tri(l - 1, l - 1 + d)] -
                          head[l - 1] * head[l - 1 + d] +
                          win[l] * win[l + d];
  }

  // diagonal loading: += DL * trace/16
  float tr = 0.0f;
#pragma unroll
  for (int l = 0; l < 16; ++l) tr += Ru[tri(l, l)];
  const float dl = tr * (0.05f / 16.0f);
#pragma unroll
  for (int l = 0; l < 16; ++l) Ru[tri(l, l)] += dl;

  // x (unscaled window means): X[l] = sum_{j=l}^{l+112} xf[j]
  float X[16];
  {
    float s = Sall;
#pragma unroll
    for (int i = 1; i < 16; ++i) s -= win[i];
    X[0] = s;
#pragma unroll
    for (int l = 1; l < 16; ++l) X[l] = X[l - 1] - head[l - 1] + win[l];
  }

  // ---- Cholesky R = L L^T, L[i][j] stored at Ru[tri(j,i)] ----
  float inv[16];
#pragma unroll
  for (int j = 0; j < 16; ++j) {
    float d = Ru[tri(j, j)];
#pragma unroll
    for (int p = 0; p < j; ++p) d = fmaf(-Ru[tri(p, j)], Ru[tri(p, j)], d);
    float Ljj = sqrtf(d);
    inv[j] = 1.0f / Ljj;
    Ru[tri(j, j)] = Ljj;
#pragma unroll
    for (int i = j + 1; i < 16; ++i) {
      float s = Ru[tri(j, i)];
#pragma unroll
      for (int p = 0; p < j; ++p) s = fmaf(-Ru[tri(p, i)], Ru[tri(p, j)], s);
      Ru[tri(j, i)] = s * inv[j];
    }
  }

  // forward solve L y = 1
  float yv[16];
#pragma unroll
  for (int i = 0; i < 16; ++i) {
    float s = 1.0f;
#pragma unroll
    for (int j = 0; j < i; ++j) s = fmaf(-Ru[tri(j, i)], yv[j], s);
    yv[i] = s * inv[i];
  }
  // back solve L^T u = y
  float u[16];
#pragma unroll
  for (int i = 15; i >= 0; --i) {
    float s = yv[i];
#pragma unroll
    for (int j = i + 1; j < 16; ++j) s = fmaf(-Ru[tri(i, j)], u[j], s);
    u[i] = s * inv[i];
  }

  float su = 0.0f, dot = 0.0f;
#pragma unroll
  for (int i = 0; i < 16; ++i) {
    su += u[i];
    dot = fmaf(u[i], X[i], dot);
  }
  // y = dot/(M*su + 1e-10)  (exactly matches reference up to scale algebra)
  out[(size_t)b * kZX + z * kNX + x] = dot / (113.0f * su + 1e-10f);
}

}  // namespace

extern "C" void kernel_launch(void* const* d_in, const int* in_sizes, int n_in,
                              void* d_out, int out_size, void* d_ws,
                              size_t ws_size, hipStream_t stream) {
  const float* rf   = (const float*)d_in[0];
  const float* t0   = (const float*)d_in[1];
  const float* d_tx = (const float*)d_in[2];
  const float* d_rx = (const float*)d_in[3];
  const float* fs   = (const float*)d_in[4];
  // d_in[5] = f0 (unused), d_in[7] = apod (unused by reference)
  const float* c0   = (const float*)d_in[6];
  float* out = (float*)d_out;

  dim3 grid(kB * kNZ);   // 512 blocks: one per (b, z) row
  dim3 block(kTPB);
  hipLaunchKernelGGL(mvb_kernel, grid, block, 0, stream, rf, t0, d_tx, d_rx,
                     fs, c0, out);
}